// Round 2
// baseline (96.776 us; speedup 1.0000x reference)
//
#include <hip/hip_runtime.h>
#include <hip/hip_fp16.h>

#define BB 16
#define NN 4096
#define CC 6
#define NSEG (BB * NN)          // 65536 points per direction-role
#define NTILE 128               // 4096 cols / 32
#define NBLK 1024               // min-kernel blocks

using half8  = __attribute__((ext_vector_type(8))) _Float16;
using half4  = __attribute__((ext_vector_type(4))) _Float16;

// ---- explicit-register asm inner loop ------------------------------------
// 32x32x8 MFMA map, double-buffered accumulators (no RAW s_nops needed):
//   zc v[32:47]
//   dA0 v[48:63]  dA1 v[64:79]     (folded late in same phase)
//   dB0 v[80:95]  dB1 v[96:111]    (folded early in NEXT phase; init +FLT_MAX)
//   tiles T0 v[112:113] T1 v[114:115] T2 v[116:117] T3 v[118:119]
//   addr v[120:121]
// Fold gaps: FOLDA reads dA written ~40+ issue-cycles earlier (2 loads +
// FOLDB(32cyc) + wait + 2 MFMA + 2 loads in between); FOLDB reads dB written
// in the previous phase. MFMA dest-read hazard (~32 cyc) covered with zero nops.
#define FOLDA \
  "v_min3_f32 %[m0],  %[m0],  v48, v64\n\t" \
  "v_min3_f32 %[m1],  %[m1],  v49, v65\n\t" \
  "v_min3_f32 %[m2],  %[m2],  v50, v66\n\t" \
  "v_min3_f32 %[m3],  %[m3],  v51, v67\n\t" \
  "v_min3_f32 %[m4],  %[m4],  v52, v68\n\t" \
  "v_min3_f32 %[m5],  %[m5],  v53, v69\n\t" \
  "v_min3_f32 %[m6],  %[m6],  v54, v70\n\t" \
  "v_min3_f32 %[m7],  %[m7],  v55, v71\n\t" \
  "v_min3_f32 %[m8],  %[m8],  v56, v72\n\t" \
  "v_min3_f32 %[m9],  %[m9],  v57, v73\n\t" \
  "v_min3_f32 %[m10], %[m10], v58, v74\n\t" \
  "v_min3_f32 %[m11], %[m11], v59, v75\n\t" \
  "v_min3_f32 %[m12], %[m12], v60, v76\n\t" \
  "v_min3_f32 %[m13], %[m13], v61, v77\n\t" \
  "v_min3_f32 %[m14], %[m14], v62, v78\n\t" \
  "v_min3_f32 %[m15], %[m15], v63, v79\n\t"

#define FOLDB \
  "v_min3_f32 %[m0],  %[m0],  v80, v96\n\t" \
  "v_min3_f32 %[m1],  %[m1],  v81, v97\n\t" \
  "v_min3_f32 %[m2],  %[m2],  v82, v98\n\t" \
  "v_min3_f32 %[m3],  %[m3],  v83, v99\n\t" \
  "v_min3_f32 %[m4],  %[m4],  v84, v100\n\t" \
  "v_min3_f32 %[m5],  %[m5],  v85, v101\n\t" \
  "v_min3_f32 %[m6],  %[m6],  v86, v102\n\t" \
  "v_min3_f32 %[m7],  %[m7],  v87, v103\n\t" \
  "v_min3_f32 %[m8],  %[m8],  v88, v104\n\t" \
  "v_min3_f32 %[m9],  %[m9],  v89, v105\n\t" \
  "v_min3_f32 %[m10], %[m10], v90, v106\n\t" \
  "v_min3_f32 %[m11], %[m11], v91, v107\n\t" \
  "v_min3_f32 %[m12], %[m12], v92, v108\n\t" \
  "v_min3_f32 %[m13], %[m13], v93, v109\n\t" \
  "v_min3_f32 %[m14], %[m14], v94, v110\n\t" \
  "v_min3_f32 %[m15], %[m15], v95, v111\n\t"

// ws layout:
//   half8 Af[2][BB][NN] @ 0     (2 MB) A entry per ROW point:
//        slots 0-3 = (-2h0,-2h1,-2h2,1)  [K0-3, lanes 0-31]
//        slots 4-7 = (1,0,0,0)           [K4-7, lanes 32-63]
//   half8 Bf[2][BB][NN] @ 2 MB  (2 MB) B entry per COL point:
//        slots 0-3 = (h0,h1,h2,hi)       [K0-3, lanes 0-31]
//        slots 4-7 = (lo,0,0,0)          [K4-7, lanes 32-63]
//   float rx[2][BB][NN] @ 4 MB  (512 KB) row-point |h|^2 fp32 (absorbs tail over-read)
//   float bpart[NBLK]   @ 4.5MB (4 KB) per-block partials
//   unsigned counter    @ 4.5MB+4KB  (ticket for last-block reduce; prep zeroes it)

__global__ __launch_bounds__(256) void chamfer_prep_kernel(
    const float* __restrict__ xg, const float* __restrict__ yg,
    half8* __restrict__ Af, half8* __restrict__ Bf, float* __restrict__ rx,
    unsigned* __restrict__ counter)
{
    const int p   = blockIdx.x * 256 + threadIdx.x;   // 0..131071
    const int dir = p >> 16;
    const int rem = p & (NSEG - 1);
    const float* __restrict__ R  = dir ? yg : xg;   // row cloud (min FOR its points)
    const float* __restrict__ Cl = dir ? xg : yg;   // col cloud (min OVER its points)

    if (p == 0) *counter = 0u;    // ws is re-poisoned every iteration

    {   // row side
        const float c0 = R[(size_t)rem * CC + 0];
        const float c1 = R[(size_t)rem * CC + 1];
        const float c2 = R[(size_t)rem * CC + 2];
        const _Float16 h0 = (_Float16)c0, h1 = (_Float16)c1, h2 = (_Float16)c2;
        const float f0 = (float)h0, f1 = (float)h1, f2 = (float)h2;
        rx[p] = fmaf(f0, f0, fmaf(f1, f1, f2 * f2));
        half8 a = { (_Float16)(-2.0f) * h0, (_Float16)(-2.0f) * h1,
                    (_Float16)(-2.0f) * h2, (_Float16)1.0f, (_Float16)1.0f,
                    (_Float16)0.0f, (_Float16)0.0f, (_Float16)0.0f };
        Af[p] = a;
    }
    {   // col side: ry as hi/lo fp16 pair in K-slots 3,4
        const float c0 = Cl[(size_t)rem * CC + 0];
        const float c1 = Cl[(size_t)rem * CC + 1];
        const float c2 = Cl[(size_t)rem * CC + 2];
        const _Float16 h0 = (_Float16)c0, h1 = (_Float16)c1, h2 = (_Float16)c2;
        const float f0 = (float)h0, f1 = (float)h1, f2 = (float)h2;
        const float r  = fmaf(f0, f0, fmaf(f1, f1, f2 * f2));
        const _Float16 hi = (_Float16)r;
        const _Float16 lo = (_Float16)(r - (float)hi);
        half8 bfr = { h0, h1, h2, hi, lo,
                      (_Float16)0.0f, (_Float16)0.0f, (_Float16)0.0f };
        Bf[p] = bfr;
    }
}

// grid = 1024 blocks x 256 thr (4 waves). wave -> (dir, b, rowgroup of 32); full j-range.
// 32 phases of 128 cols each; 4 tiles (512B/wave each) in flight, split vmcnt(2)
// gates give >= 3/4-phase prefetch distance. Final reduction runs in the LAST
// block (device-scope ticket), summation order identical to the old final kernel.
__global__ __launch_bounds__(256, 4) void chamfer_min_kernel(
    const half8* __restrict__ Af, const half8* __restrict__ Bf,
    const float* __restrict__ rx, float* __restrict__ bpart,
    unsigned* __restrict__ counter, float* __restrict__ out)
{
    const int bid  = blockIdx.x;
    const int dir  = bid & 1;
    const int b    = (bid >> 1) & 15;
    const int gq   = bid >> 5;                 // 0..31
    const int tid  = threadIdx.x;
    const int w    = tid >> 6;
    const int lane = tid & 63;
    const int l31  = lane & 31;
    const int hf   = lane >> 5;                // K-half select (K0-3 vs K4-7)
    const int g    = gq * 4 + w;               // rowgroup 0..127

    const size_t base = ((size_t)dir << 16) + ((size_t)b << 12);

    // A fragment: 8 B per lane; lanes 0-31 take slots 0-3, lanes 32-63 slots 4-7.
    const half4 a = *reinterpret_cast<const half4*>(
        reinterpret_cast<const char*>(Af + base + (size_t)g * 32 + l31) + hf * 8);

    // per-lane byte address of this block's B stream: point l31, K-half hf
    const unsigned long long ba =
        (unsigned long long)(reinterpret_cast<const char*>(Bf + base))
        + (unsigned)(l31 * 16 + hf * 8);
    const unsigned alo = (unsigned)ba;
    const unsigned ahi = (unsigned)(ba >> 32);

    float m0  = 3.4e38f, m1  = 3.4e38f, m2  = 3.4e38f, m3  = 3.4e38f;
    float m4  = 3.4e38f, m5  = 3.4e38f, m6  = 3.4e38f, m7  = 3.4e38f;
    float m8  = 3.4e38f, m9  = 3.4e38f, m10 = 3.4e38f, m11 = 3.4e38f;
    float m12 = 3.4e38f, m13 = 3.4e38f, m14 = 3.4e38f, m15 = 3.4e38f;
    int cnt = 32;

    asm volatile(
        // zero-C tile v[32:47], built once, never rewritten
        "v_mov_b32 v32, 0\n\t"  "v_mov_b32 v33, 0\n\t"
        "v_mov_b32 v34, 0\n\t"  "v_mov_b32 v35, 0\n\t"
        "v_mov_b32 v36, 0\n\t"  "v_mov_b32 v37, 0\n\t"
        "v_mov_b32 v38, 0\n\t"  "v_mov_b32 v39, 0\n\t"
        "v_mov_b32 v40, 0\n\t"  "v_mov_b32 v41, 0\n\t"
        "v_mov_b32 v42, 0\n\t"  "v_mov_b32 v43, 0\n\t"
        "v_mov_b32 v44, 0\n\t"  "v_mov_b32 v45, 0\n\t"
        "v_mov_b32 v46, 0\n\t"  "v_mov_b32 v47, 0\n\t"
        // dB init to +FLT_MAX so phase 0's FOLDB is harmless
        "v_mov_b32 v80,  0x7f7fffff\n\t" "v_mov_b32 v81,  0x7f7fffff\n\t"
        "v_mov_b32 v82,  0x7f7fffff\n\t" "v_mov_b32 v83,  0x7f7fffff\n\t"
        "v_mov_b32 v84,  0x7f7fffff\n\t" "v_mov_b32 v85,  0x7f7fffff\n\t"
        "v_mov_b32 v86,  0x7f7fffff\n\t" "v_mov_b32 v87,  0x7f7fffff\n\t"
        "v_mov_b32 v88,  0x7f7fffff\n\t" "v_mov_b32 v89,  0x7f7fffff\n\t"
        "v_mov_b32 v90,  0x7f7fffff\n\t" "v_mov_b32 v91,  0x7f7fffff\n\t"
        "v_mov_b32 v92,  0x7f7fffff\n\t" "v_mov_b32 v93,  0x7f7fffff\n\t"
        "v_mov_b32 v94,  0x7f7fffff\n\t" "v_mov_b32 v95,  0x7f7fffff\n\t"
        "v_mov_b32 v96,  0x7f7fffff\n\t" "v_mov_b32 v97,  0x7f7fffff\n\t"
        "v_mov_b32 v98,  0x7f7fffff\n\t" "v_mov_b32 v99,  0x7f7fffff\n\t"
        "v_mov_b32 v100, 0x7f7fffff\n\t" "v_mov_b32 v101, 0x7f7fffff\n\t"
        "v_mov_b32 v102, 0x7f7fffff\n\t" "v_mov_b32 v103, 0x7f7fffff\n\t"
        "v_mov_b32 v104, 0x7f7fffff\n\t" "v_mov_b32 v105, 0x7f7fffff\n\t"
        "v_mov_b32 v106, 0x7f7fffff\n\t" "v_mov_b32 v107, 0x7f7fffff\n\t"
        "v_mov_b32 v108, 0x7f7fffff\n\t" "v_mov_b32 v109, 0x7f7fffff\n\t"
        "v_mov_b32 v110, 0x7f7fffff\n\t" "v_mov_b32 v111, 0x7f7fffff\n\t"
        // addr = ba
        "v_mov_b32 v120, %[alo]\n\t"
        "v_mov_b32 v121, %[ahi]\n\t"
        "s_nop 1\n\t"
        // preload tiles 0-3 (phase 0 data), 8 B per lane each
        "global_load_dwordx2 v[112:113], v[120:121], off\n\t"
        "global_load_dwordx2 v[114:115], v[120:121], off offset:512\n\t"
        "global_load_dwordx2 v[116:117], v[120:121], off offset:1024\n\t"
        "global_load_dwordx2 v[118:119], v[120:121], off offset:1536\n\t"
        "LOOP%=:\n\t"
        "s_waitcnt vmcnt(2)\n\t"                                     // T0,T1 ready
        "v_mfma_f32_32x32x8_f16 v[48:63], %[fa], v[112:113], v[32:47]\n\t"
        "v_mfma_f32_32x32x8_f16 v[64:79], %[fa], v[114:115], v[32:47]\n\t"
        "v_add_co_u32 v120, vcc, 0x800, v120\n\t"
        "v_addc_co_u32 v121, vcc, 0, v121, vcc\n\t"
        "s_nop 1\n\t"
        "global_load_dwordx2 v[112:113], v[120:121], off\n\t"        // next T0
        "global_load_dwordx2 v[114:115], v[120:121], off offset:512\n\t"
        FOLDB                                                        // prev phase's dB
        "s_waitcnt vmcnt(2)\n\t"                                     // T2,T3 ready
        "v_mfma_f32_32x32x8_f16 v[80:95],  %[fa], v[116:117], v[32:47]\n\t"
        "v_mfma_f32_32x32x8_f16 v[96:111], %[fa], v[118:119], v[32:47]\n\t"
        "global_load_dwordx2 v[116:117], v[120:121], off offset:1024\n\t"
        "global_load_dwordx2 v[118:119], v[120:121], off offset:1536\n\t"
        FOLDA                                                        // this phase's dA
        "s_sub_u32 %[cnt], %[cnt], 1\n\t"
        "s_cmp_lg_u32 %[cnt], 0\n\t"
        "s_cbranch_scc1 LOOP%=\n\t"
        // drain: last phase's dB still unfolded
        "s_nop 7\n\t"
        "s_nop 7\n\t"
        FOLDB
        "s_waitcnt vmcnt(0)"
        : [m0] "+v"(m0),  [m1] "+v"(m1),  [m2] "+v"(m2),  [m3] "+v"(m3),
          [m4] "+v"(m4),  [m5] "+v"(m5),  [m6] "+v"(m6),  [m7] "+v"(m7),
          [m8] "+v"(m8),  [m9] "+v"(m9),  [m10] "+v"(m10), [m11] "+v"(m11),
          [m12] "+v"(m12), [m13] "+v"(m13), [m14] "+v"(m14), [m15] "+v"(m15),
          [cnt] "+s"(cnt)
        : [fa] "v"(a), [alo] "v"(alo), [ahi] "v"(ahi)
        : "memory", "vcc", "scc",
          "v32","v33","v34","v35","v36","v37","v38","v39",
          "v40","v41","v42","v43","v44","v45","v46","v47",
          "v48","v49","v50","v51","v52","v53","v54","v55",
          "v56","v57","v58","v59","v60","v61","v62","v63",
          "v64","v65","v66","v67","v68","v69","v70","v71",
          "v72","v73","v74","v75","v76","v77","v78","v79",
          "v80","v81","v82","v83","v84","v85","v86","v87",
          "v88","v89","v90","v91","v92","v93","v94","v95",
          "v96","v97","v98","v99","v100","v101","v102","v103",
          "v104","v105","v106","v107","v108","v109","v110","v111",
          "v112","v113","v114","v115","v116","v117","v118","v119",
          "v120","v121");

    float mn[16] = { m0, m1, m2, m3, m4, m5, m6, m7,
                     m8, m9, m10, m11, m12, m13, m14, m15 };

    // cross-lane min over the 32 cols within each half (halves hold different rows)
    #pragma unroll
    for (int s = 0; s < 16; ++s) {
        float v = mn[s];
        v = fminf(v, __shfl_xor(v, 1,  64));
        v = fminf(v, __shfl_xor(v, 2,  64));
        v = fminf(v, __shfl_xor(v, 4,  64));
        v = fminf(v, __shfl_xor(v, 8,  64));
        v = fminf(v, __shfl_xor(v, 16, 64));
        mn[s] = v;
    }

    // add rx per row, sum this half's 16 rows
    const float* __restrict__ rxb = rx + base + (size_t)g * 32;
    float s16 = 0.0f;
    #pragma unroll
    for (int s = 0; s < 16; ++s) {
        const int row = (s & 3) + 8 * (s >> 2) + 4 * hf;  // C/D row map (32x32 shape)
        s16 += fmaxf(mn[s] + rxb[row], 0.0f);             // clamp fp noise at 0
    }

    __shared__ float hsum[8];
    __shared__ unsigned lastS;
    if (l31 == 0) hsum[w * 2 + hf] = s16;
    __syncthreads();
    if (tid == 0) {
        float t = 0.0f;
        #pragma unroll
        for (int k = 0; k < 8; ++k) t += hsum[k];
        bpart[bid] = t;
        __threadfence();                           // release: bpart visible device-wide
        const unsigned ticket = atomicAdd(counter, 1u);
        lastS = (ticket == NBLK - 1) ? 1u : 0u;
    }
    __syncthreads();

    // deterministic final reduction in the last-arriving block
    // (identical summation order to the former chamfer_final_kernel -> bit-exact)
    if (lastS) {
        __threadfence();                           // acquire side
        float s =
            __hip_atomic_load(&bpart[tid],       __ATOMIC_RELAXED, __HIP_MEMORY_SCOPE_AGENT) +
            __hip_atomic_load(&bpart[tid + 256], __ATOMIC_RELAXED, __HIP_MEMORY_SCOPE_AGENT) +
            __hip_atomic_load(&bpart[tid + 512], __ATOMIC_RELAXED, __HIP_MEMORY_SCOPE_AGENT) +
            __hip_atomic_load(&bpart[tid + 768], __ATOMIC_RELAXED, __HIP_MEMORY_SCOPE_AGENT);
        for (int off = 32; off > 0; off >>= 1)
            s += __shfl_down(s, off, 64);
        __shared__ float wsum[4];
        if ((tid & 63) == 0) wsum[tid >> 6] = s;
        __syncthreads();
        if (tid == 0)
            out[0] = (wsum[0] + wsum[1] + wsum[2] + wsum[3]) * (1.0f / NSEG);
    }
}

extern "C" void kernel_launch(void* const* d_in, const int* in_sizes, int n_in,
                              void* d_out, int out_size, void* d_ws, size_t ws_size,
                              hipStream_t stream) {
    const float* x = (const float*)d_in[0];
    const float* y = (const float*)d_in[1];
    float* out = (float*)d_out;

    half8* Af = (half8*)d_ws;
    half8* Bf = (half8*)((char*)d_ws + (size_t)2 * NSEG * sizeof(half8));
    float* rx = (float*)((char*)d_ws + (size_t)4 * NSEG * sizeof(half8));
    float* bpart = (float*)((char*)rx + (size_t)2 * NSEG * sizeof(float));
    unsigned* counter = (unsigned*)((char*)bpart + (size_t)NBLK * sizeof(float));

    chamfer_prep_kernel<<<2 * NSEG / 256, 256, 0, stream>>>(x, y, Af, Bf, rx, counter);
    chamfer_min_kernel<<<NBLK, 256, 0, stream>>>(Af, Bf, rx, bpart, counter, out);
}

// Round 4
// 80.328 us; speedup vs baseline: 1.2047x; 1.2047x over previous
//
#include <hip/hip_runtime.h>
#include <hip/hip_fp16.h>

#define BB 16
#define NN 4096
#define CC 6
#define NSEG (BB * NN)          // 65536 points per direction-role
#define NTILE 128               // 4096 cols / 32
#define NBLK 512                // min-kernel blocks (512 x 512thr, 2 blocks/CU)

using half8  = __attribute__((ext_vector_type(8))) _Float16;
using half4  = __attribute__((ext_vector_type(4))) _Float16;

// ---- explicit-register asm inner loop ------------------------------------
// 32x32x8 MFMA map, double-buffered accumulators (proven round-2 skeleton),
// B operands now from LDS (ds_read_b64, counted lgkmcnt gates):
//   zc v[32:47]
//   dA0 v[48:63]  dA1 v[64:79]     (folded late in same phase)
//   dB0 v[80:95]  dB1 v[96:111]    (folded early in NEXT phase; init +FLT_MAX)
//   tiles T0 v[112:113] T1 v[114:115] T2 v[116:117] T3 v[118:119]
//   r (LDS byte addr) v120
#define FOLDA \
  "v_min3_f32 %[m0],  %[m0],  v48, v64\n\t" \
  "v_min3_f32 %[m1],  %[m1],  v49, v65\n\t" \
  "v_min3_f32 %[m2],  %[m2],  v50, v66\n\t" \
  "v_min3_f32 %[m3],  %[m3],  v51, v67\n\t" \
  "v_min3_f32 %[m4],  %[m4],  v52, v68\n\t" \
  "v_min3_f32 %[m5],  %[m5],  v53, v69\n\t" \
  "v_min3_f32 %[m6],  %[m6],  v54, v70\n\t" \
  "v_min3_f32 %[m7],  %[m7],  v55, v71\n\t" \
  "v_min3_f32 %[m8],  %[m8],  v56, v72\n\t" \
  "v_min3_f32 %[m9],  %[m9],  v57, v73\n\t" \
  "v_min3_f32 %[m10], %[m10], v58, v74\n\t" \
  "v_min3_f32 %[m11], %[m11], v59, v75\n\t" \
  "v_min3_f32 %[m12], %[m12], v60, v76\n\t" \
  "v_min3_f32 %[m13], %[m13], v61, v77\n\t" \
  "v_min3_f32 %[m14], %[m14], v62, v78\n\t" \
  "v_min3_f32 %[m15], %[m15], v63, v79\n\t"

#define FOLDB \
  "v_min3_f32 %[m0],  %[m0],  v80, v96\n\t" \
  "v_min3_f32 %[m1],  %[m1],  v81, v97\n\t" \
  "v_min3_f32 %[m2],  %[m2],  v82, v98\n\t" \
  "v_min3_f32 %[m3],  %[m3],  v83, v99\n\t" \
  "v_min3_f32 %[m4],  %[m4],  v84, v100\n\t" \
  "v_min3_f32 %[m5],  %[m5],  v85, v101\n\t" \
  "v_min3_f32 %[m6],  %[m6],  v86, v102\n\t" \
  "v_min3_f32 %[m7],  %[m7],  v87, v103\n\t" \
  "v_min3_f32 %[m8],  %[m8],  v88, v104\n\t" \
  "v_min3_f32 %[m9],  %[m9],  v89, v105\n\t" \
  "v_min3_f32 %[m10], %[m10], v90, v106\n\t" \
  "v_min3_f32 %[m11], %[m11], v91, v107\n\t" \
  "v_min3_f32 %[m12], %[m12], v92, v108\n\t" \
  "v_min3_f32 %[m13], %[m13], v93, v109\n\t" \
  "v_min3_f32 %[m14], %[m14], v94, v110\n\t" \
  "v_min3_f32 %[m15], %[m15], v95, v111\n\t"

// ws layout:
//   half8 Af[2][BB][NN] @ 0     (2 MB) A entry per ROW point:
//        slots 0-3 = (-2h0,-2h1,-2h2,1)  [K0-3, lanes 0-31]
//        slots 4-7 = (1,0,0,0)           [K4-7, lanes 32-63]
//   half8 Bf[2][BB][NN] @ 2 MB  (2 MB) B entry per COL point:
//        slots 0-3 = (h0,h1,h2,hi)       [K0-3, lanes 0-31]
//        slots 4-7 = (lo,0,0,0)          [K4-7, lanes 32-63]
//   float rx[2][BB][NN] @ 4 MB  (512 KB) row-point |h|^2 fp32
//   float bpart[NBLK]   @ 4.5MB (2 KB) per-block partials
//   unsigned counter    @ 4.5MB+2KB  (ticket for last-block reduce; prep zeroes it)

__global__ __launch_bounds__(256) void chamfer_prep_kernel(
    const float* __restrict__ xg, const float* __restrict__ yg,
    half8* __restrict__ Af, half8* __restrict__ Bf, float* __restrict__ rx,
    unsigned* __restrict__ counter)
{
    const int p   = blockIdx.x * 256 + threadIdx.x;   // 0..131071
    const int dir = p >> 16;
    const int rem = p & (NSEG - 1);
    const float* __restrict__ R  = dir ? yg : xg;   // row cloud (min FOR its points)
    const float* __restrict__ Cl = dir ? xg : yg;   // col cloud (min OVER its points)

    if (p == 0) *counter = 0u;    // ws is re-poisoned every iteration

    {   // row side
        const float c0 = R[(size_t)rem * CC + 0];
        const float c1 = R[(size_t)rem * CC + 1];
        const float c2 = R[(size_t)rem * CC + 2];
        const _Float16 h0 = (_Float16)c0, h1 = (_Float16)c1, h2 = (_Float16)c2;
        const float f0 = (float)h0, f1 = (float)h1, f2 = (float)h2;
        rx[p] = fmaf(f0, f0, fmaf(f1, f1, f2 * f2));
        half8 a = { (_Float16)(-2.0f) * h0, (_Float16)(-2.0f) * h1,
                    (_Float16)(-2.0f) * h2, (_Float16)1.0f, (_Float16)1.0f,
                    (_Float16)0.0f, (_Float16)0.0f, (_Float16)0.0f };
        Af[p] = a;
    }
    {   // col side: ry as hi/lo fp16 pair in K-slots 3,4
        const float c0 = Cl[(size_t)rem * CC + 0];
        const float c1 = Cl[(size_t)rem * CC + 1];
        const float c2 = Cl[(size_t)rem * CC + 2];
        const _Float16 h0 = (_Float16)c0, h1 = (_Float16)c1, h2 = (_Float16)c2;
        const float f0 = (float)h0, f1 = (float)h1, f2 = (float)h2;
        const float r  = fmaf(f0, f0, fmaf(f1, f1, f2 * f2));
        const _Float16 hi = (_Float16)r;
        const _Float16 lo = (_Float16)(r - (float)hi);
        half8 bfr = { h0, h1, h2, hi, lo,
                      (_Float16)0.0f, (_Float16)0.0f, (_Float16)0.0f };
        Bf[p] = bfr;
    }
}

// grid = 512 blocks x 512 thr (8 waves). block -> (dir, b, gq of 16); each of the
// 8 waves owns one rowgroup (32 rows), full j-range. The block's 64 KB B-stream
// is staged to LDS ONCE (split K-half-major so ds_read_b64 is stride-8 = 2-way
// bank aliasing = free), then the inner loop reads B from LDS (~120 cyc latency,
// hidden by the 1-phase prefetch + counted lgkmcnt gates).
// LDS 67712 B/block -> 2 blocks/CU (135 KB), 16 waves/CU, all 512 blocks resident.
__global__ __launch_bounds__(512, 4) void chamfer_min_kernel(
    const half8* __restrict__ Af, const half8* __restrict__ Bf,
    const float* __restrict__ rx, float* __restrict__ bpart,
    unsigned* __restrict__ counter, float* __restrict__ out)
{
    // data [0, 65536) ; epilogue scratch [65536, 65664) ; pad so the last-iter
    // prefetch over-read (up to byte ~67576, reads only) stays in bounds
    __shared__ unsigned long long shv[8464];   // 67712 B

    const int bid  = blockIdx.x;
    const int dir  = bid & 1;
    const int b    = (bid >> 1) & 15;
    const int gq   = bid >> 5;                 // 0..15
    const int tid  = threadIdx.x;
    const int w    = tid >> 6;                 // wave 0..7
    const int lane = tid & 63;
    const int l31  = lane & 31;
    const int hf   = lane >> 5;                // K-half select (K0-3 vs K4-7)
    const int g    = gq * 8 + w;               // rowgroup 0..127

    const size_t base = ((size_t)dir << 16) + ((size_t)b << 12);

    // ---- stage the block's B-stream (64 KB) into LDS, split K-half-major ----
    // shv[0..4095]      = low 8 B of point q  (K-slots 0-3)
    // shv[4096..8191]   = high 8 B of point q (K-slots 4-7)
    {
        const half8* __restrict__ Bseg = Bf + base;
        #pragma unroll
        for (int k = 0; k < 8; ++k) {
            const int idx = tid + k * 512;              // 0..4095
            const half8 v = Bseg[idx];                  // one dwordx4, coalesced
            const unsigned long long* pv =
                reinterpret_cast<const unsigned long long*>(&v);
            shv[idx]        = pv[0];
            shv[4096 + idx] = pv[1];
        }
    }

    // A fragment: 8 B per lane; lanes 0-31 take slots 0-3, lanes 32-63 slots 4-7.
    const half4 a = *reinterpret_cast<const half4*>(
        reinterpret_cast<const char*>(Af + base + (size_t)g * 32 + l31) + hf * 8);

    __syncthreads();

    // per-lane LDS byte address: half hf, point l31 of tile 0
    const unsigned ldsbase = (unsigned)(unsigned long long)(&shv[0]);
    const unsigned rinit   = ldsbase + (unsigned)(hf * 32768 + l31 * 8);

    float m0  = 3.4e38f, m1  = 3.4e38f, m2  = 3.4e38f, m3  = 3.4e38f;
    float m4  = 3.4e38f, m5  = 3.4e38f, m6  = 3.4e38f, m7  = 3.4e38f;
    float m8  = 3.4e38f, m9  = 3.4e38f, m10 = 3.4e38f, m11 = 3.4e38f;
    float m12 = 3.4e38f, m13 = 3.4e38f, m14 = 3.4e38f, m15 = 3.4e38f;
    int cnt = 32;

    asm volatile(
        // zero-C tile v[32:47], built once, never rewritten
        "v_mov_b32 v32, 0\n\t"  "v_mov_b32 v33, 0\n\t"
        "v_mov_b32 v34, 0\n\t"  "v_mov_b32 v35, 0\n\t"
        "v_mov_b32 v36, 0\n\t"  "v_mov_b32 v37, 0\n\t"
        "v_mov_b32 v38, 0\n\t"  "v_mov_b32 v39, 0\n\t"
        "v_mov_b32 v40, 0\n\t"  "v_mov_b32 v41, 0\n\t"
        "v_mov_b32 v42, 0\n\t"  "v_mov_b32 v43, 0\n\t"
        "v_mov_b32 v44, 0\n\t"  "v_mov_b32 v45, 0\n\t"
        "v_mov_b32 v46, 0\n\t"  "v_mov_b32 v47, 0\n\t"
        // dB init to +FLT_MAX so phase 0's FOLDB is harmless
        "v_mov_b32 v80,  0x7f7fffff\n\t" "v_mov_b32 v81,  0x7f7fffff\n\t"
        "v_mov_b32 v82,  0x7f7fffff\n\t" "v_mov_b32 v83,  0x7f7fffff\n\t"
        "v_mov_b32 v84,  0x7f7fffff\n\t" "v_mov_b32 v85,  0x7f7fffff\n\t"
        "v_mov_b32 v86,  0x7f7fffff\n\t" "v_mov_b32 v87,  0x7f7fffff\n\t"
        "v_mov_b32 v88,  0x7f7fffff\n\t" "v_mov_b32 v89,  0x7f7fffff\n\t"
        "v_mov_b32 v90,  0x7f7fffff\n\t" "v_mov_b32 v91,  0x7f7fffff\n\t"
        "v_mov_b32 v92,  0x7f7fffff\n\t" "v_mov_b32 v93,  0x7f7fffff\n\t"
        "v_mov_b32 v94,  0x7f7fffff\n\t" "v_mov_b32 v95,  0x7f7fffff\n\t"
        "v_mov_b32 v96,  0x7f7fffff\n\t" "v_mov_b32 v97,  0x7f7fffff\n\t"
        "v_mov_b32 v98,  0x7f7fffff\n\t" "v_mov_b32 v99,  0x7f7fffff\n\t"
        "v_mov_b32 v100, 0x7f7fffff\n\t" "v_mov_b32 v101, 0x7f7fffff\n\t"
        "v_mov_b32 v102, 0x7f7fffff\n\t" "v_mov_b32 v103, 0x7f7fffff\n\t"
        "v_mov_b32 v104, 0x7f7fffff\n\t" "v_mov_b32 v105, 0x7f7fffff\n\t"
        "v_mov_b32 v106, 0x7f7fffff\n\t" "v_mov_b32 v107, 0x7f7fffff\n\t"
        "v_mov_b32 v108, 0x7f7fffff\n\t" "v_mov_b32 v109, 0x7f7fffff\n\t"
        "v_mov_b32 v110, 0x7f7fffff\n\t" "v_mov_b32 v111, 0x7f7fffff\n\t"
        // r = LDS addr of this lane's half/point for tile 0
        "v_mov_b32 v120, %[rini]\n\t"
        // preload phase-0 tiles (4 x ds_read_b64)
        "ds_read_b64 v[112:113], v120\n\t"
        "ds_read_b64 v[114:115], v120 offset:256\n\t"
        "ds_read_b64 v[116:117], v120 offset:512\n\t"
        "ds_read_b64 v[118:119], v120 offset:768\n\t"
        "LOOP%=:\n\t"
        "s_waitcnt lgkmcnt(2)\n\t"                               // T0,T1 ready
        "v_mfma_f32_32x32x8_f16 v[48:63], %[fa], v[112:113], v[32:47]\n\t"
        "v_mfma_f32_32x32x8_f16 v[64:79], %[fa], v[114:115], v[32:47]\n\t"
        "ds_read_b64 v[112:113], v120 offset:1024\n\t"           // next-phase T0
        "ds_read_b64 v[114:115], v120 offset:1280\n\t"
        FOLDB                                                    // prev phase's dB
        "s_waitcnt lgkmcnt(2)\n\t"                               // T2,T3 ready
        "v_mfma_f32_32x32x8_f16 v[80:95],  %[fa], v[116:117], v[32:47]\n\t"
        "v_mfma_f32_32x32x8_f16 v[96:111], %[fa], v[118:119], v[32:47]\n\t"
        "ds_read_b64 v[116:117], v120 offset:1536\n\t"           // next-phase T2
        "ds_read_b64 v[118:119], v120 offset:1792\n\t"
        "v_add_u32 v120, 0x400, v120\n\t"
        FOLDA                                                    // this phase's dA
        "s_sub_u32 %[cnt], %[cnt], 1\n\t"
        "s_cmp_lg_u32 %[cnt], 0\n\t"
        "s_cbranch_scc1 LOOP%=\n\t"
        // drain: last phase's dB still unfolded
        "s_nop 7\n\t"
        "s_nop 7\n\t"
        FOLDB
        "s_waitcnt lgkmcnt(0)"
        : [m0] "+v"(m0),  [m1] "+v"(m1),  [m2] "+v"(m2),  [m3] "+v"(m3),
          [m4] "+v"(m4),  [m5] "+v"(m5),  [m6] "+v"(m6),  [m7] "+v"(m7),
          [m8] "+v"(m8),  [m9] "+v"(m9),  [m10] "+v"(m10), [m11] "+v"(m11),
          [m12] "+v"(m12), [m13] "+v"(m13), [m14] "+v"(m14), [m15] "+v"(m15),
          [cnt] "+s"(cnt)
        : [fa] "v"(a), [rini] "v"(rinit)
        : "memory", "vcc", "scc",
          "v32","v33","v34","v35","v36","v37","v38","v39",
          "v40","v41","v42","v43","v44","v45","v46","v47",
          "v48","v49","v50","v51","v52","v53","v54","v55",
          "v56","v57","v58","v59","v60","v61","v62","v63",
          "v64","v65","v66","v67","v68","v69","v70","v71",
          "v72","v73","v74","v75","v76","v77","v78","v79",
          "v80","v81","v82","v83","v84","v85","v86","v87",
          "v88","v89","v90","v91","v92","v93","v94","v95",
          "v96","v97","v98","v99","v100","v101","v102","v103",
          "v104","v105","v106","v107","v108","v109","v110","v111",
          "v112","v113","v114","v115","v116","v117","v118","v119",
          "v120");

    float mn[16] = { m0, m1, m2, m3, m4, m5, m6, m7,
                     m8, m9, m10, m11, m12, m13, m14, m15 };

    // cross-lane min over the 32 cols within each half (halves hold different rows)
    #pragma unroll
    for (int s = 0; s < 16; ++s) {
        float v = mn[s];
        v = fminf(v, __shfl_xor(v, 1,  64));
        v = fminf(v, __shfl_xor(v, 2,  64));
        v = fminf(v, __shfl_xor(v, 4,  64));
        v = fminf(v, __shfl_xor(v, 8,  64));
        v = fminf(v, __shfl_xor(v, 16, 64));
        mn[s] = v;
    }

    // add rx per row, sum this half's 16 rows
    const float* __restrict__ rxb = rx + base + (size_t)g * 32;
    float s16 = 0.0f;
    #pragma unroll
    for (int s = 0; s < 16; ++s) {
        const int row = (s & 3) + 8 * (s >> 2) + 4 * hf;  // C/D row map (32x32 shape)
        s16 += fmaxf(mn[s] + rxb[row], 0.0f);             // clamp fp noise at 0
    }

    // epilogue scratch in the shv tail (beyond the 65536 B of data):
    // hsum = shv[8192..8199] (16 floats), flag at shv[8200], wsum = shv[8201..8204]
    float*    hsum     = (float*)&shv[8192];
    unsigned* lastFlag = (unsigned*)&shv[8200];
    float*    wsum     = (float*)&shv[8201];

    __syncthreads();                 // asm done in all waves before reusing LDS
    if (l31 == 0) hsum[w * 2 + hf] = s16;
    __syncthreads();
    if (tid == 0) {
        float t = 0.0f;
        #pragma unroll
        for (int k = 0; k < 16; ++k) t += hsum[k];
        bpart[bid] = t;
        __threadfence();                           // release: bpart visible device-wide
        const unsigned ticket = atomicAdd(counter, 1u);
        *lastFlag = (ticket == NBLK - 1) ? 1u : 0u;
    }
    __syncthreads();

    // final reduction in the last-arriving block (512 threads, 512 partials)
    if (*lastFlag) {
        __threadfence();                           // acquire side
        float s = __hip_atomic_load(&bpart[tid], __ATOMIC_RELAXED,
                                    __HIP_MEMORY_SCOPE_AGENT);
        for (int off = 32; off > 0; off >>= 1)
            s += __shfl_down(s, off, 64);
        if ((tid & 63) == 0) wsum[tid >> 6] = s;
        __syncthreads();
        if (tid == 0) {
            float t = 0.0f;
            #pragma unroll
            for (int k = 0; k < 8; ++k) t += wsum[k];
            out[0] = t * (1.0f / NSEG);
        }
    }
}

extern "C" void kernel_launch(void* const* d_in, const int* in_sizes, int n_in,
                              void* d_out, int out_size, void* d_ws, size_t ws_size,
                              hipStream_t stream) {
    const float* x = (const float*)d_in[0];
    const float* y = (const float*)d_in[1];
    float* out = (float*)d_out;

    half8* Af = (half8*)d_ws;
    half8* Bf = (half8*)((char*)d_ws + (size_t)2 * NSEG * sizeof(half8));
    float* rx = (float*)((char*)d_ws + (size_t)4 * NSEG * sizeof(half8));
    float* bpart = (float*)((char*)rx + (size_t)2 * NSEG * sizeof(float));
    unsigned* counter = (unsigned*)((char*)bpart + (size_t)NBLK * sizeof(float));

    chamfer_prep_kernel<<<2 * NSEG / 256, 256, 0, stream>>>(x, y, Af, Bf, rx, counter);
    chamfer_min_kernel<<<NBLK, 512, 0, stream>>>(Af, Bf, rx, bpart, counter, out);
}

// Round 6
// 79.272 us; speedup vs baseline: 1.2208x; 1.0133x over previous
//
#include <hip/hip_runtime.h>
#include <hip/hip_fp16.h>

#define BB 16
#define NN 4096
#define CC 6
#define NSEG (BB * NN)          // 65536 points per direction-role
#define NTILE 128               // 4096 cols / 32
#define NBLK 512                // min-kernel blocks (512 x 512thr, 2 blocks/CU)

using half8  = __attribute__((ext_vector_type(8))) _Float16;
using half4  = __attribute__((ext_vector_type(4))) _Float16;

// ---- explicit-register asm inner loop ------------------------------------
// 32x32x8 MFMA map, double-buffered accumulators, 8-tile (2-phase) LDS
// prefetch pipeline with static 16-bit offsets:
//   zc v[32:47]
//   dA0 v[48:63]  dA1 v[64:79]     (folded late in same phase)
//   dB0 v[80:95]  dB1 v[96:111]    (folded early in NEXT phase; init +FLT_MAX)
//   tile group0 v[112:119] (even phases)  group1 v[120:127] (odd phases)
//   LDS base addr lives in %[rini] (+0x1000 per 4-phase body)
// Gates are lgkmcnt(6): 8 DS ops in flight, wait only for the oldest 2.
#define FOLDA \
  "v_min3_f32 %[m0],  %[m0],  v48, v64\n\t" \
  "v_min3_f32 %[m1],  %[m1],  v49, v65\n\t" \
  "v_min3_f32 %[m2],  %[m2],  v50, v66\n\t" \
  "v_min3_f32 %[m3],  %[m3],  v51, v67\n\t" \
  "v_min3_f32 %[m4],  %[m4],  v52, v68\n\t" \
  "v_min3_f32 %[m5],  %[m5],  v53, v69\n\t" \
  "v_min3_f32 %[m6],  %[m6],  v54, v70\n\t" \
  "v_min3_f32 %[m7],  %[m7],  v55, v71\n\t" \
  "v_min3_f32 %[m8],  %[m8],  v56, v72\n\t" \
  "v_min3_f32 %[m9],  %[m9],  v57, v73\n\t" \
  "v_min3_f32 %[m10], %[m10], v58, v74\n\t" \
  "v_min3_f32 %[m11], %[m11], v59, v75\n\t" \
  "v_min3_f32 %[m12], %[m12], v60, v76\n\t" \
  "v_min3_f32 %[m13], %[m13], v61, v77\n\t" \
  "v_min3_f32 %[m14], %[m14], v62, v78\n\t" \
  "v_min3_f32 %[m15], %[m15], v63, v79\n\t"

#define FOLDB \
  "v_min3_f32 %[m0],  %[m0],  v80, v96\n\t" \
  "v_min3_f32 %[m1],  %[m1],  v81, v97\n\t" \
  "v_min3_f32 %[m2],  %[m2],  v82, v98\n\t" \
  "v_min3_f32 %[m3],  %[m3],  v83, v99\n\t" \
  "v_min3_f32 %[m4],  %[m4],  v84, v100\n\t" \
  "v_min3_f32 %[m5],  %[m5],  v85, v101\n\t" \
  "v_min3_f32 %[m6],  %[m6],  v86, v102\n\t" \
  "v_min3_f32 %[m7],  %[m7],  v87, v103\n\t" \
  "v_min3_f32 %[m8],  %[m8],  v88, v104\n\t" \
  "v_min3_f32 %[m9],  %[m9],  v89, v105\n\t" \
  "v_min3_f32 %[m10], %[m10], v90, v106\n\t" \
  "v_min3_f32 %[m11], %[m11], v91, v107\n\t" \
  "v_min3_f32 %[m12], %[m12], v92, v108\n\t" \
  "v_min3_f32 %[m13], %[m13], v93, v109\n\t" \
  "v_min3_f32 %[m14], %[m14], v94, v110\n\t" \
  "v_min3_f32 %[m15], %[m15], v95, v111\n\t"

// One phase: consume 4 tiles of a fixed register group, prefetch the same
// slots for phase+2 at static offsets OA..OD (relative to current body base).
// Register groups are hardcoded per macro (CPP can't splice a macro into
// multiple macro arguments - that's what broke round 5's build).
#define PHASE_G0(OA, OB, OC, OD)                                            \
  "s_waitcnt lgkmcnt(6)\n\t"                                                \
  "v_mfma_f32_32x32x8_f16 v[48:63], %[fa], v[112:113], v[32:47]\n\t"        \
  "v_mfma_f32_32x32x8_f16 v[64:79], %[fa], v[114:115], v[32:47]\n\t"        \
  "ds_read_b64 v[112:113], %[rini] offset:" OA "\n\t"                       \
  "ds_read_b64 v[114:115], %[rini] offset:" OB "\n\t"                       \
  FOLDB                                                                     \
  "s_waitcnt lgkmcnt(6)\n\t"                                                \
  "v_mfma_f32_32x32x8_f16 v[80:95],  %[fa], v[116:117], v[32:47]\n\t"       \
  "v_mfma_f32_32x32x8_f16 v[96:111], %[fa], v[118:119], v[32:47]\n\t"       \
  "ds_read_b64 v[116:117], %[rini] offset:" OC "\n\t"                       \
  "ds_read_b64 v[118:119], %[rini] offset:" OD "\n\t"                       \
  FOLDA

#define PHASE_G1(OA, OB, OC, OD)                                            \
  "s_waitcnt lgkmcnt(6)\n\t"                                                \
  "v_mfma_f32_32x32x8_f16 v[48:63], %[fa], v[120:121], v[32:47]\n\t"        \
  "v_mfma_f32_32x32x8_f16 v[64:79], %[fa], v[122:123], v[32:47]\n\t"        \
  "ds_read_b64 v[120:121], %[rini] offset:" OA "\n\t"                       \
  "ds_read_b64 v[122:123], %[rini] offset:" OB "\n\t"                       \
  FOLDB                                                                     \
  "s_waitcnt lgkmcnt(6)\n\t"                                                \
  "v_mfma_f32_32x32x8_f16 v[80:95],  %[fa], v[124:125], v[32:47]\n\t"       \
  "v_mfma_f32_32x32x8_f16 v[96:111], %[fa], v[126:127], v[32:47]\n\t"       \
  "ds_read_b64 v[124:125], %[rini] offset:" OC "\n\t"                       \
  "ds_read_b64 v[126:127], %[rini] offset:" OD "\n\t"                       \
  FOLDA

// ws layout:
//   half8 Af[2][BB][NN] @ 0     (2 MB) A entry per ROW point:
//        slots 0-3 = (-2h0,-2h1,-2h2,1)  [K0-3, lanes 0-31]
//        slots 4-7 = (1,0,0,0)           [K4-7, lanes 32-63]
//   half8 Bf[2][BB][NN] @ 2 MB  (2 MB) B entry per COL point:
//        slots 0-3 = (h0,h1,h2,hi)       [K0-3, lanes 0-31]
//        slots 4-7 = (lo,0,0,0)          [K4-7, lanes 32-63]
//   float rx[2][BB][NN] @ 4 MB  (512 KB) row-point |h|^2 fp32
//   float bpart[NBLK]   @ 4.5MB (2 KB) per-block partials
//   unsigned counter    @ 4.5MB+2KB  (ticket for last-block reduce; prep zeroes it)

__global__ __launch_bounds__(256) void chamfer_prep_kernel(
    const float* __restrict__ xg, const float* __restrict__ yg,
    half8* __restrict__ Af, half8* __restrict__ Bf, float* __restrict__ rx,
    unsigned* __restrict__ counter)
{
    const int p   = blockIdx.x * 256 + threadIdx.x;   // 0..131071
    const int dir = p >> 16;
    const int rem = p & (NSEG - 1);
    const float* __restrict__ R  = dir ? yg : xg;   // row cloud (min FOR its points)
    const float* __restrict__ Cl = dir ? xg : yg;   // col cloud (min OVER its points)

    if (p == 0) *counter = 0u;    // ws is re-poisoned every iteration

    {   // row side
        const float c0 = R[(size_t)rem * CC + 0];
        const float c1 = R[(size_t)rem * CC + 1];
        const float c2 = R[(size_t)rem * CC + 2];
        const _Float16 h0 = (_Float16)c0, h1 = (_Float16)c1, h2 = (_Float16)c2;
        const float f0 = (float)h0, f1 = (float)h1, f2 = (float)h2;
        rx[p] = fmaf(f0, f0, fmaf(f1, f1, f2 * f2));
        half8 a = { (_Float16)(-2.0f) * h0, (_Float16)(-2.0f) * h1,
                    (_Float16)(-2.0f) * h2, (_Float16)1.0f, (_Float16)1.0f,
                    (_Float16)0.0f, (_Float16)0.0f, (_Float16)0.0f };
        Af[p] = a;
    }
    {   // col side: ry as hi/lo fp16 pair in K-slots 3,4
        const float c0 = Cl[(size_t)rem * CC + 0];
        const float c1 = Cl[(size_t)rem * CC + 1];
        const float c2 = Cl[(size_t)rem * CC + 2];
        const _Float16 h0 = (_Float16)c0, h1 = (_Float16)c1, h2 = (_Float16)c2;
        const float f0 = (float)h0, f1 = (float)h1, f2 = (float)h2;
        const float r  = fmaf(f0, f0, fmaf(f1, f1, f2 * f2));
        const _Float16 hi = (_Float16)r;
        const _Float16 lo = (_Float16)(r - (float)hi);
        half8 bfr = { h0, h1, h2, hi, lo,
                      (_Float16)0.0f, (_Float16)0.0f, (_Float16)0.0f };
        Bf[p] = bfr;
    }
}

// grid = 512 blocks x 512 thr (8 waves). block -> (dir, b, gq of 16); each of the
// 8 waves owns one rowgroup (32 rows), full j-range. Block's 64 KB B-stream is
// staged to LDS once (K-half-major). Inner loop: 8 ds_read_b64 in flight,
// lgkmcnt(6) gates -> 2 full phases of latency slack. Tail prefetches
// (phases 32,33) land in the LDS pad: in-bounds, unused.
// LDS 67712 B/block -> 2 blocks/CU, 16 waves/CU, all 512 blocks resident.
__global__ __launch_bounds__(512, 4) void chamfer_min_kernel(
    const half8* __restrict__ Af, const half8* __restrict__ Bf,
    const float* __restrict__ rx, float* __restrict__ bpart,
    unsigned* __restrict__ counter, float* __restrict__ out)
{
    // data [0, 65536) ; epilogue scratch + tail-prefetch pad [65536, 67712)
    // (tail prefetch reads reach byte <= 67583 < 67712)
    __shared__ unsigned long long shv[8464];   // 67712 B

    const int bid  = blockIdx.x;
    const int dir  = bid & 1;
    const int b    = (bid >> 1) & 15;
    const int gq   = bid >> 5;                 // 0..15
    const int tid  = threadIdx.x;
    const int w    = tid >> 6;                 // wave 0..7
    const int lane = tid & 63;
    const int l31  = lane & 31;
    const int hf   = lane >> 5;                // K-half select (K0-3 vs K4-7)
    const int g    = gq * 8 + w;               // rowgroup 0..127

    const size_t base = ((size_t)dir << 16) + ((size_t)b << 12);

    // ---- stage the block's B-stream (64 KB) into LDS, split K-half-major ----
    // shv[0..4095]      = low 8 B of point q  (K-slots 0-3)
    // shv[4096..8191]   = high 8 B of point q (K-slots 4-7)
    {
        const half8* __restrict__ Bseg = Bf + base;
        #pragma unroll
        for (int k = 0; k < 8; ++k) {
            const int idx = tid + k * 512;              // 0..4095
            const half8 v = Bseg[idx];                  // one dwordx4, coalesced
            const unsigned long long* pv =
                reinterpret_cast<const unsigned long long*>(&v);
            shv[idx]        = pv[0];
            shv[4096 + idx] = pv[1];
        }
    }

    // A fragment: 8 B per lane; lanes 0-31 take slots 0-3, lanes 32-63 slots 4-7.
    const half4 a = *reinterpret_cast<const half4*>(
        reinterpret_cast<const char*>(Af + base + (size_t)g * 32 + l31) + hf * 8);

    __syncthreads();

    // per-lane LDS byte address: half hf, point l31 of tile 0
    const unsigned ldsbase = (unsigned)(unsigned long long)(&shv[0]);
    unsigned r = ldsbase + (unsigned)(hf * 32768 + l31 * 8);

    float m0  = 3.4e38f, m1  = 3.4e38f, m2  = 3.4e38f, m3  = 3.4e38f;
    float m4  = 3.4e38f, m5  = 3.4e38f, m6  = 3.4e38f, m7  = 3.4e38f;
    float m8  = 3.4e38f, m9  = 3.4e38f, m10 = 3.4e38f, m11 = 3.4e38f;
    float m12 = 3.4e38f, m13 = 3.4e38f, m14 = 3.4e38f, m15 = 3.4e38f;
    int cnt = 8;

    asm volatile(
        // zero-C tile v[32:47], built once, never rewritten
        "v_mov_b32 v32, 0\n\t"  "v_mov_b32 v33, 0\n\t"
        "v_mov_b32 v34, 0\n\t"  "v_mov_b32 v35, 0\n\t"
        "v_mov_b32 v36, 0\n\t"  "v_mov_b32 v37, 0\n\t"
        "v_mov_b32 v38, 0\n\t"  "v_mov_b32 v39, 0\n\t"
        "v_mov_b32 v40, 0\n\t"  "v_mov_b32 v41, 0\n\t"
        "v_mov_b32 v42, 0\n\t"  "v_mov_b32 v43, 0\n\t"
        "v_mov_b32 v44, 0\n\t"  "v_mov_b32 v45, 0\n\t"
        "v_mov_b32 v46, 0\n\t"  "v_mov_b32 v47, 0\n\t"
        // dB init to +FLT_MAX so phase 0's FOLDB is harmless
        "v_mov_b32 v80,  0x7f7fffff\n\t" "v_mov_b32 v81,  0x7f7fffff\n\t"
        "v_mov_b32 v82,  0x7f7fffff\n\t" "v_mov_b32 v83,  0x7f7fffff\n\t"
        "v_mov_b32 v84,  0x7f7fffff\n\t" "v_mov_b32 v85,  0x7f7fffff\n\t"
        "v_mov_b32 v86,  0x7f7fffff\n\t" "v_mov_b32 v87,  0x7f7fffff\n\t"
        "v_mov_b32 v88,  0x7f7fffff\n\t" "v_mov_b32 v89,  0x7f7fffff\n\t"
        "v_mov_b32 v90,  0x7f7fffff\n\t" "v_mov_b32 v91,  0x7f7fffff\n\t"
        "v_mov_b32 v92,  0x7f7fffff\n\t" "v_mov_b32 v93,  0x7f7fffff\n\t"
        "v_mov_b32 v94,  0x7f7fffff\n\t" "v_mov_b32 v95,  0x7f7fffff\n\t"
        "v_mov_b32 v96,  0x7f7fffff\n\t" "v_mov_b32 v97,  0x7f7fffff\n\t"
        "v_mov_b32 v98,  0x7f7fffff\n\t" "v_mov_b32 v99,  0x7f7fffff\n\t"
        "v_mov_b32 v100, 0x7f7fffff\n\t" "v_mov_b32 v101, 0x7f7fffff\n\t"
        "v_mov_b32 v102, 0x7f7fffff\n\t" "v_mov_b32 v103, 0x7f7fffff\n\t"
        "v_mov_b32 v104, 0x7f7fffff\n\t" "v_mov_b32 v105, 0x7f7fffff\n\t"
        "v_mov_b32 v106, 0x7f7fffff\n\t" "v_mov_b32 v107, 0x7f7fffff\n\t"
        "v_mov_b32 v108, 0x7f7fffff\n\t" "v_mov_b32 v109, 0x7f7fffff\n\t"
        "v_mov_b32 v110, 0x7f7fffff\n\t" "v_mov_b32 v111, 0x7f7fffff\n\t"
        // preload phases 0 and 1 (8 ds_read_b64 in flight)
        "ds_read_b64 v[112:113], %[rini]\n\t"
        "ds_read_b64 v[114:115], %[rini] offset:256\n\t"
        "ds_read_b64 v[116:117], %[rini] offset:512\n\t"
        "ds_read_b64 v[118:119], %[rini] offset:768\n\t"
        "ds_read_b64 v[120:121], %[rini] offset:1024\n\t"
        "ds_read_b64 v[122:123], %[rini] offset:1280\n\t"
        "ds_read_b64 v[124:125], %[rini] offset:1536\n\t"
        "ds_read_b64 v[126:127], %[rini] offset:1792\n\t"
        "LOOP%=:\n\t"
        // body = 4 phases; prefetch offsets are (phase+2)*1024 + {0,256,512,768}
        PHASE_G0("2048", "2304", "2560", "2816")
        PHASE_G1("3072", "3328", "3584", "3840")
        PHASE_G0("4096", "4352", "4608", "4864")
        PHASE_G1("5120", "5376", "5632", "5888")
        "v_add_u32 %[rini], 0x1000, %[rini]\n\t"
        "s_sub_u32 %[cnt], %[cnt], 1\n\t"
        "s_cmp_lg_u32 %[cnt], 0\n\t"
        "s_cbranch_scc1 LOOP%=\n\t"
        // drain: last phase's dB still unfolded (dB MFMAs covered by FOLDA above)
        "s_nop 7\n\t"
        "s_nop 7\n\t"
        FOLDB
        "s_waitcnt lgkmcnt(0)"
        : [m0] "+v"(m0),  [m1] "+v"(m1),  [m2] "+v"(m2),  [m3] "+v"(m3),
          [m4] "+v"(m4),  [m5] "+v"(m5),  [m6] "+v"(m6),  [m7] "+v"(m7),
          [m8] "+v"(m8),  [m9] "+v"(m9),  [m10] "+v"(m10), [m11] "+v"(m11),
          [m12] "+v"(m12), [m13] "+v"(m13), [m14] "+v"(m14), [m15] "+v"(m15),
          [cnt] "+s"(cnt), [rini] "+v"(r)
        : [fa] "v"(a)
        : "memory", "vcc", "scc",
          "v32","v33","v34","v35","v36","v37","v38","v39",
          "v40","v41","v42","v43","v44","v45","v46","v47",
          "v48","v49","v50","v51","v52","v53","v54","v55",
          "v56","v57","v58","v59","v60","v61","v62","v63",
          "v64","v65","v66","v67","v68","v69","v70","v71",
          "v72","v73","v74","v75","v76","v77","v78","v79",
          "v80","v81","v82","v83","v84","v85","v86","v87",
          "v88","v89","v90","v91","v92","v93","v94","v95",
          "v96","v97","v98","v99","v100","v101","v102","v103",
          "v104","v105","v106","v107","v108","v109","v110","v111",
          "v112","v113","v114","v115","v116","v117","v118","v119",
          "v120","v121","v122","v123","v124","v125","v126","v127");

    float mn[16] = { m0, m1, m2, m3, m4, m5, m6, m7,
                     m8, m9, m10, m11, m12, m13, m14, m15 };

    // cross-lane min over the 32 cols within each half (halves hold different rows)
    #pragma unroll
    for (int s = 0; s < 16; ++s) {
        float v = mn[s];
        v = fminf(v, __shfl_xor(v, 1,  64));
        v = fminf(v, __shfl_xor(v, 2,  64));
        v = fminf(v, __shfl_xor(v, 4,  64));
        v = fminf(v, __shfl_xor(v, 8,  64));
        v = fminf(v, __shfl_xor(v, 16, 64));
        mn[s] = v;
    }

    // add rx per row, sum this half's 16 rows
    const float* __restrict__ rxb = rx + base + (size_t)g * 32;
    float s16 = 0.0f;
    #pragma unroll
    for (int s = 0; s < 16; ++s) {
        const int row = (s & 3) + 8 * (s >> 2) + 4 * hf;  // C/D row map (32x32 shape)
        s16 += fmaxf(mn[s] + rxb[row], 0.0f);             // clamp fp noise at 0
    }

    // epilogue scratch in the shv tail (beyond the 65536 B of data):
    // hsum = shv[8192..8199] (16 floats), flag at shv[8200], wsum = shv[8201..8204]
    float*    hsum     = (float*)&shv[8192];
    unsigned* lastFlag = (unsigned*)&shv[8200];
    float*    wsum     = (float*)&shv[8201];

    __syncthreads();                 // asm done in all waves before reusing LDS
    if (l31 == 0) hsum[w * 2 + hf] = s16;
    __syncthreads();
    if (tid == 0) {
        float t = 0.0f;
        #pragma unroll
        for (int k = 0; k < 16; ++k) t += hsum[k];
        bpart[bid] = t;
        __threadfence();                           // release: bpart visible device-wide
        const unsigned ticket = atomicAdd(counter, 1u);
        *lastFlag = (ticket == NBLK - 1) ? 1u : 0u;
    }
    __syncthreads();

    // final reduction in the last-arriving block (512 threads, 512 partials)
    if (*lastFlag) {
        __threadfence();                           // acquire side
        float s = __hip_atomic_load(&bpart[tid], __ATOMIC_RELAXED,
                                    __HIP_MEMORY_SCOPE_AGENT);
        for (int off = 32; off > 0; off >>= 1)
            s += __shfl_down(s, off, 64);
        if ((tid & 63) == 0) wsum[tid >> 6] = s;
        __syncthreads();
        if (tid == 0) {
            float t = 0.0f;
            #pragma unroll
            for (int k = 0; k < 8; ++k) t += wsum[k];
            out[0] = t * (1.0f / NSEG);
        }
    }
}

extern "C" void kernel_launch(void* const* d_in, const int* in_sizes, int n_in,
                              void* d_out, int out_size, void* d_ws, size_t ws_size,
                              hipStream_t stream) {
    const float* x = (const float*)d_in[0];
    const float* y = (const float*)d_in[1];
    float* out = (float*)d_out;

    half8* Af = (half8*)d_ws;
    half8* Bf = (half8*)((char*)d_ws + (size_t)2 * NSEG * sizeof(half8));
    float* rx = (float*)((char*)d_ws + (size_t)4 * NSEG * sizeof(half8));
    float* bpart = (float*)((char*)rx + (size_t)2 * NSEG * sizeof(float));
    unsigned* counter = (unsigned*)((char*)bpart + (size_t)NBLK * sizeof(float));

    chamfer_prep_kernel<<<2 * NSEG / 256, 256, 0, stream>>>(x, y, Af, Bf, rx, counter);
    chamfer_min_kernel<<<NBLK, 512, 0, stream>>>(Af, Bf, rx, bpart, counter, out);
}